// Round 1
// baseline (216.440 us; speedup 1.0000x reference)
//
#include <hip/hip_runtime.h>

// Problem geometry (fixed by the reference):
//   probs: (B=2, C=2, D=32, H=512, W=512) fp32
//   mask : (B=2, D=32, H=512, W=512)      int32, values {0,1,2}; 2 = ignore -> class 0
// Output: scalar fp32 = mean over all B*C*D*H*W of (probs - onehot)^2
//
// All loads are exactly-once streaming: 128 MiB probs + 64 MiB mask = 201.3 MB.
// Memory roofline at 6.3 TB/s achievable = ~32 us for the partial kernel.
static constexpr long long DHW       = 32LL * 512 * 512;   // 8388608 = 1<<23 floats
static constexpr long long N_SPATIAL = 2LL * DHW;          // 16777216 = 1<<24
static constexpr long long N_TOTAL   = 2LL * N_SPATIAL;    // 33554432 = 1<<25

// R6: ITERS 16->8, GRID 1024->2048. Halves live load-result VGPRs (192->96)
// so occupancy rises from ~2 to ~4 waves/SIMD; smoother VMEM/compute overlap.
// 24 x 16B loads in flight per wave is still >> Little's-law requirement.
static constexpr int GRID  = 2048;   // 8 blocks/CU
static constexpr int BLOCK = 256;
static constexpr int ITERS = 8;      // 24 NT loads (24 KB) in flight per wave
static constexpr unsigned NVEC    = (unsigned)(N_SPATIAL / 4);   // 4194304 float4 chunks
static constexpr unsigned STRIDE  = (unsigned)GRID * BLOCK;      // 524288
static constexpr unsigned DHW4    = 1u << 21;                    // DHW in float4 units
static_assert((long long)NVEC == (long long)ITERS * STRIDE, "exact trip count");

// Native clang vector types — required by __builtin_nontemporal_load
// (HIP_vector_type float4/int4 are structs and are rejected).
typedef float fx4 __attribute__((ext_vector_type(4)));
typedef int   ix4 __attribute__((ext_vector_type(4)));

__global__ __launch_bounds__(BLOCK) void betti_mse_partial(const float* __restrict__ probs,
                                                           const int*   __restrict__ mask,
                                                           double*      __restrict__ partial) {
    const unsigned v0 = blockIdx.x * BLOCK + threadIdx.x;   // float4 index, < 2^19..2^22
    const fx4* __restrict__ p4 = reinterpret_cast<const fx4*>(probs);
    const ix4* __restrict__ m4 = reinterpret_cast<const ix4*>(mask);

    // Batch ALL loads up front, NONTEMPORAL (global_load_dwordx4 ... nt):
    // R5 established nt lifts the cache-allocation throttle on the read path.
    // R6: pure 32-bit index math. Spatial float4 idx v < 2^22, batch bit is
    // bit 21, and base4 = b*(C*DHW/4) + rest4 collapses to v + (v & 1<<21).
    fx4 P0[ITERS], P1[ITERS];
    ix4 M[ITERS];
    #pragma unroll
    for (int i = 0; i < ITERS; ++i) {
        const unsigned v    = v0 + (unsigned)i * STRIDE;  // spatial float4 idx
        const unsigned base = v + (v & DHW4);             // channel-0 float4 idx
        P0[i] = __builtin_nontemporal_load(p4 + base);
        P1[i] = __builtin_nontemporal_load(p4 + base + DHW4);
        M[i]  = __builtin_nontemporal_load(m4 + v);
    }

    // 4 accumulators: FMA dep chains of 16 (vs 64 with 2 accs) — fully hidden.
    float acc0 = 0.0f, acc1 = 0.0f, acc2 = 0.0f, acc3 = 0.0f;
    #pragma unroll
    for (int i = 0; i < ITERS; ++i) {
        const float t0 = (M[i].x == 1) ? 1.0f : 0.0f;
        const float t1 = (M[i].y == 1) ? 1.0f : 0.0f;
        const float t2 = (M[i].z == 1) ? 1.0f : 0.0f;
        const float t3 = (M[i].w == 1) ? 1.0f : 0.0f;
        float d;
        d = P0[i].x - (1.0f - t0); acc0 += d * d;
        d = P0[i].y - (1.0f - t1); acc1 += d * d;
        d = P0[i].z - (1.0f - t2); acc2 += d * d;
        d = P0[i].w - (1.0f - t3); acc3 += d * d;
        d = P1[i].x - t0;          acc0 += d * d;
        d = P1[i].y - t1;          acc1 += d * d;
        d = P1[i].z - t2;          acc2 += d * d;
        d = P1[i].w - t3;          acc3 += d * d;
    }
    float local = (acc0 + acc1) + (acc2 + acc3);

    #pragma unroll
    for (int off = 32; off > 0; off >>= 1)
        local += __shfl_down(local, off, 64);

    __shared__ float wsum[4];
    const int lane = threadIdx.x & 63;
    const int wid  = threadIdx.x >> 6;
    if (lane == 0) wsum[wid] = local;
    __syncthreads();
    if (threadIdx.x == 0)
        partial[blockIdx.x] = (double)(wsum[0] + wsum[1] + wsum[2] + wsum[3]);
}

__global__ __launch_bounds__(BLOCK) void betti_mse_final(const double* __restrict__ partial,
                                                         float* __restrict__ out) {
    double local = 0.0;
    #pragma unroll
    for (int k = 0; k < GRID / BLOCK; ++k)   // 8 partials per thread
        local += partial[threadIdx.x + k * BLOCK];

    #pragma unroll
    for (int off = 32; off > 0; off >>= 1)
        local += __shfl_down(local, off, 64);

    __shared__ double wsum[4];
    const int lane = threadIdx.x & 63;
    const int wid  = threadIdx.x >> 6;
    if (lane == 0) wsum[wid] = local;
    __syncthreads();
    if (threadIdx.x == 0)
        out[0] = (float)((wsum[0] + wsum[1] + wsum[2] + wsum[3]) / (double)N_TOTAL);
}

extern "C" void kernel_launch(void* const* d_in, const int* in_sizes, int n_in,
                              void* d_out, int out_size, void* d_ws, size_t ws_size,
                              hipStream_t stream) {
    const float* probs   = (const float*)d_in[0];
    const int*   mask    = (const int*)d_in[1];
    float*       out     = (float*)d_out;
    double*      partial = (double*)d_ws;   // GRID doubles = 16 KB scratch

    betti_mse_partial<<<GRID, BLOCK, 0, stream>>>(probs, mask, partial);
    betti_mse_final<<<1, BLOCK, 0, stream>>>(partial, out);
}